// Round 2
// baseline (868.087 us; speedup 1.0000x reference)
//
#include <hip/hip_runtime.h>

typedef unsigned short u16;
typedef __attribute__((ext_vector_type(4))) unsigned short u16x4;
typedef __attribute__((ext_vector_type(8))) short short8;
typedef __attribute__((ext_vector_type(4))) float f32x4;

#define D_MODEL 1024
#define D_FF    4096
#define NB      16
#define NTOK    1024
#define NEXP    8

// round-to-nearest-even fp32 -> bf16
__device__ __forceinline__ u16 f2bf(float f) {
  union { float f; unsigned u; } v; v.f = f;
  unsigned r = v.u + 0x7FFFu + ((v.u >> 16) & 1u);
  return (u16)(r >> 16);
}

// async global->LDS, 16B per lane; LDS dest is wave-uniform base + lane*16
__device__ __forceinline__ void gld16(const void* g, void* l) {
  __builtin_amdgcn_global_load_lds(
      (const __attribute__((address_space(1))) unsigned int*)g,
      (__attribute__((address_space(3))) unsigned int*)l,
      16, 0, 0);
}

// s_waitcnt immediates (gfx9 encoding: vmcnt[3:0]|expcnt[6:4]|lgkmcnt[11:8])
#define WAITCNT_VM8 0x0F78  // vmcnt(8), lgkm/exp unconstrained
#define WAITCNT_VM0 0x0F70  // vmcnt(0)

// ---------------------------------------------------------------------------
// x fp32 -> bf16 + per-(b,h) column sums (for router mean) via atomics.
__global__ void xcvt_kernel(const float* __restrict__ x, u16* __restrict__ xbf,
                            float* __restrict__ sums) {
  const int b = blockIdx.y;
  const int n0 = blockIdx.x * 16;
  const int t = threadIdx.x;
  const int h0 = t * 4;
  const size_t base = ((size_t)b * NTOK + n0) * D_MODEL + h0;
  const float* xp = x + base;
  u16* op = xbf + base;
  float a0 = 0.f, a1 = 0.f, a2 = 0.f, a3 = 0.f;
#pragma unroll
  for (int r = 0; r < 16; ++r) {
    float4 v = *(const float4*)(xp + (size_t)r * D_MODEL);
    a0 += v.x; a1 += v.y; a2 += v.z; a3 += v.w;
    u16x4 o;
    o.x = f2bf(v.x); o.y = f2bf(v.y); o.z = f2bf(v.z); o.w = f2bf(v.w);
    *(u16x4*)(op + (size_t)r * D_MODEL) = o;
  }
  float* s = sums + b * D_MODEL + h0;
  atomicAdd(s + 0, a0); atomicAdd(s + 1, a1);
  atomicAdd(s + 2, a2); atomicAdd(s + 3, a3);
}

// ---------------------------------------------------------------------------
// Router: scores[b][e] = dot(sum_x[b]/N, Wr[:,e]) + br[e]; top-1 argmax per b.
__global__ void router_kernel(const float* __restrict__ sums,
                              const float* __restrict__ Wr,
                              const float* __restrict__ br,
                              int* __restrict__ top1, int* __restrict__ used) {
  __shared__ float sc[NB][NEXP];
  const int t = threadIdx.x;
  const int b = t >> 3, e = t & 7;
  if (t < NEXP) used[t] = 0;
  const float* s = sums + b * D_MODEL;
  float acc = 0.f;
  for (int h = 0; h < D_MODEL; ++h) acc += s[h] * Wr[h * NEXP + e];
  sc[b][e] = acc * (1.0f / (float)NTOK) + br[e];
  __syncthreads();
  if (t < NB) {
    float best = sc[t][0]; int bi = 0;
#pragma unroll
    for (int e2 = 1; e2 < NEXP; ++e2) {
      float v = sc[t][e2];
      if (v > best) { best = v; bi = e2; }  // first-max wins, matches argmax
    }
    top1[t] = bi;
    used[bi] = 1;
  }
}

// ---------------------------------------------------------------------------
// Per-expert transpose + fp32->bf16: dst[c][r] = bf16(src[r][c]).
__global__ void wcvt_kernel(const float* __restrict__ src, u16* __restrict__ dst,
                            const int* __restrict__ used, int R, int C) {
  const int e = blockIdx.z;
  if (!used[e]) return;
  __shared__ float tile[64][65];
  const float* s = src + (size_t)e * R * C;
  u16* d = dst + (size_t)e * R * C;
  const int r0 = blockIdx.y * 64, c0 = blockIdx.x * 64;
  const int t = threadIdx.x;
#pragma unroll
  for (int i = 0; i < 16; ++i) {
    int idx = i * 256 + t;
    int r = idx >> 6, c = idx & 63;
    tile[r][c] = s[(size_t)(r0 + r) * C + (c0 + c)];
  }
  __syncthreads();
#pragma unroll
  for (int i = 0; i < 16; ++i) {
    int idx = i * 256 + t;
    int r = idx >> 6, c = idx & 63;
    d[(size_t)(c0 + r) * R + (r0 + c)] = f2bf(tile[c][r]);
  }
}

// ---------------------------------------------------------------------------
// Barrier-free wave-private double-buffered bf16 GEMM, B^T form.
// C[m][n] = sum_k A[m][k] * Bt[n][k]. 128x128 block tile, BK=32, 4 waves.
// Each wave owns a 64x64 out tile and stages its OWN A-half/B-half into a
// private double-buffered LDS region (16 KB/wave, 64 KB/block). No
// __syncthreads anywhere: per k-step, issue 8 global_load_lds for k+1 into
// the alternate buffer, s_waitcnt vmcnt(8) so only the current buffer's 8
// loads are drained, then ds_read_b128 + 16 MFMA. Twin-wave duplicate
// fetches hit L2/MSHR, so HBM traffic is unchanged.
template <bool RELU_BF16>
__global__ void __launch_bounds__(256)
gemm_bt(const u16* __restrict__ Abase, const u16* __restrict__ Btbase,
        const float* __restrict__ biasbase, const int* __restrict__ top1,
        void* __restrict__ OutBase, int K, int Nn) {
  // [wave][buf][mat A/B][64 rows x 32 k] = 4*2*2*2048 u16 = 64 KB
  __shared__ __align__(16) u16 smem[4 * 2 * 2 * 2048];
  const int b = blockIdx.z;
  const int e = top1[b];
  const u16* A = Abase + (size_t)b * NTOK * K;
  const u16* Bt = Btbase + (size_t)e * Nn * K;
  const float* bias = biasbase + (size_t)e * Nn;
  const int tn = blockIdx.x, tm = blockIdx.y;
  const int tid = threadIdx.x;
  const int lane = tid & 63, wave = tid >> 6;
  const int wm = wave & 1, wn = wave >> 1;

  u16* wbase = smem + wave * 8192;  // 16 KB per wave
  // buf 0: A @0, B @2048 ; buf 1: A @4096, B @6144  (u16 units)

  // staging lane map: lane -> (row = lane>>2, 16B chunk = lane&3)
  const int sr = lane >> 2, sc = lane & 3;
  const u16* gA = A + ((size_t)(tm * 128 + wm * 64 + sr)) * K + sc * 8;
  const u16* gB = Bt + ((size_t)(tn * 128 + wn * 64 + sr)) * K + sc * 8;

  // fragment addresses within the wave's private 64x32 tile
  const int fr = lane & 15, fq = lane >> 4;  // fq in 0..3
  const int fragoff = fr * 32 + fq * 8;

  f32x4 acc[4][4];
#pragma unroll
  for (int i = 0; i < 4; ++i)
#pragma unroll
    for (int j = 0; j < 4; ++j) acc[i][j] = (f32x4)(0.f);

  const int KT = K >> 5;  // k-steps of 32

  // prologue: stage k-step 0 into buf 0
  {
    u16* lA = wbase;
    u16* lB = wbase + 2048;
#pragma unroll
    for (int i = 0; i < 4; ++i) {
      gld16(gA + (size_t)i * 16 * K, lA + i * 512);
      gld16(gB + (size_t)i * 16 * K, lB + i * 512);
    }
  }

  for (int kt = 0; kt < KT; ++kt) {
    const int cur = kt & 1;
    if (kt + 1 < KT) {
      const int k0 = (kt + 1) << 5;
      u16* lA = wbase + (cur ^ 1) * 4096;
      u16* lB = lA + 2048;
#pragma unroll
      for (int i = 0; i < 4; ++i) {
        gld16(gA + (size_t)i * 16 * K + k0, lA + i * 512);
        gld16(gB + (size_t)i * 16 * K + k0, lB + i * 512);
      }
      __builtin_amdgcn_s_waitcnt(WAITCNT_VM8);  // oldest 8 (current buf) done
    } else {
      __builtin_amdgcn_s_waitcnt(WAITCNT_VM0);
    }
    __builtin_amdgcn_sched_barrier(0);

    const u16* rA = wbase + cur * 4096 + fragoff;
    const u16* rB = rA + 2048;
    short8 afrag[4], bfrag[4];
#pragma unroll
    for (int i = 0; i < 4; ++i) afrag[i] = *(const short8*)(rA + i * 512);
#pragma unroll
    for (int j = 0; j < 4; ++j) bfrag[j] = *(const short8*)(rB + j * 512);
#pragma unroll
    for (int i = 0; i < 4; ++i)
#pragma unroll
      for (int j = 0; j < 4; ++j)
        acc[i][j] = __builtin_amdgcn_mfma_f32_16x16x32_bf16(afrag[i], bfrag[j],
                                                            acc[i][j], 0, 0, 0);
  }

  // epilogue: C/D layout col=lane&15, row=4*(lane>>4)+reg
  const int row0 = tm * 128 + wm * 64 + fq * 4;
  const int col0 = tn * 128 + wn * 64 + fr;
  if constexpr (RELU_BF16) {
    u16* Out = (u16*)OutBase + (size_t)b * NTOK * Nn;
#pragma unroll
    for (int i = 0; i < 4; ++i)
#pragma unroll
      for (int j = 0; j < 4; ++j) {
        const int col = col0 + j * 16;
        const float bv = bias[col];
        const int row = row0 + i * 16;
#pragma unroll
        for (int r = 0; r < 4; ++r) {
          float v = acc[i][j][r] + bv;
          v = fmaxf(v, 0.0f);
          Out[(size_t)(row + r) * Nn + col] = f2bf(v);
        }
      }
  } else {
    float* Out = (float*)OutBase + (size_t)b * NTOK * Nn;
#pragma unroll
    for (int i = 0; i < 4; ++i)
#pragma unroll
      for (int j = 0; j < 4; ++j) {
        const int col = col0 + j * 16;
        const float bv = bias[col];
        const int row = row0 + i * 16;
#pragma unroll
        for (int r = 0; r < 4; ++r)
          Out[(size_t)(row + r) * Nn + col] = acc[i][j][r] + bv;
      }
  }
}

// ---------------------------------------------------------------------------
extern "C" void kernel_launch(void* const* d_in, const int* in_sizes, int n_in,
                              void* d_out, int out_size, void* d_ws, size_t ws_size,
                              hipStream_t stream) {
  const float* x  = (const float*)d_in[0];
  const float* Wr = (const float*)d_in[1];
  const float* br = (const float*)d_in[2];
  const float* W1 = (const float*)d_in[3];
  const float* b1 = (const float*)d_in[4];
  const float* W2 = (const float*)d_in[5];
  const float* b2 = (const float*)d_in[6];
  float* out = (float*)d_out;
  char* ws = (char*)d_ws;

  // workspace layout (~304 MB):
  int*   top1 = (int*)(ws + 0);              // 64 B
  int*   used = (int*)(ws + 64);             // 32 B
  float* sums = (float*)(ws + 4096);         // 64 KB
  u16* xbf = (u16*)(ws + (1ull << 20));      // 32 MB  [B][N][H] bf16
  u16* w1t = (u16*)(ws + (48ull << 20));     // 64 MB  [E][F][H] bf16 (W1^T)
  u16* w2t = (u16*)(ws + (112ull << 20));    // 64 MB  [E][H][F] bf16 (W2^T)
  u16* hbf = (u16*)(ws + (176ull << 20));    // 128 MB [B][N][F] bf16

  hipMemsetAsync((void*)ws, 0, 4096 + D_MODEL * NB * sizeof(float), stream);

  xcvt_kernel<<<dim3(NTOK / 16, NB), 256, 0, stream>>>(x, xbf, sums);
  router_kernel<<<1, 128, 0, stream>>>(sums, Wr, br, top1, used);
  // W1 [E][H=1024][F=4096] -> [E][F][H]
  wcvt_kernel<<<dim3(D_FF / 64, D_MODEL / 64, NEXP), 256, 0, stream>>>(
      W1, w1t, used, D_MODEL, D_FF);
  // W2 [E][F=4096][H=1024] -> [E][H][F]
  wcvt_kernel<<<dim3(D_MODEL / 64, D_FF / 64, NEXP), 256, 0, stream>>>(
      W2, w2t, used, D_FF, D_MODEL);
  // GEMM1: h = relu(x @ W1 + b1), M=1024, N=4096, K=1024, bf16 out
  gemm_bt<true><<<dim3(D_FF / 128, NTOK / 128, NB), 256, 0, stream>>>(
      xbf, w1t, b1, top1, (void*)hbf, D_MODEL, D_FF);
  // GEMM2: out = h @ W2 + b2, M=1024, N=1024, K=4096, fp32 out
  gemm_bt<false><<<dim3(D_MODEL / 128, NTOK / 128, NB), 256, 0, stream>>>(
      hbf, w2t, b2, top1, (void*)out, D_FF, D_MODEL);
}

// Round 3
// 650.186 us; speedup vs baseline: 1.3351x; 1.3351x over previous
//
#include <hip/hip_runtime.h>

typedef unsigned short u16;
typedef __attribute__((ext_vector_type(4))) unsigned short u16x4;
typedef __attribute__((ext_vector_type(8))) short short8;
typedef __attribute__((ext_vector_type(4))) float f32x4;

#define D_MODEL 1024
#define D_FF    4096
#define NB      16
#define NTOK    1024
#define NEXP    8

// round-to-nearest-even fp32 -> bf16
__device__ __forceinline__ u16 f2bf(float f) {
  union { float f; unsigned u; } v; v.f = f;
  unsigned r = v.u + 0x7FFFu + ((v.u >> 16) & 1u);
  return (u16)(r >> 16);
}

// async global->LDS, 16B per lane; LDS dest is wave-uniform base + lane*16
__device__ __forceinline__ void gld16(const void* g, void* l) {
  __builtin_amdgcn_global_load_lds(
      (const __attribute__((address_space(1))) unsigned int*)g,
      (__attribute__((address_space(3))) unsigned int*)l,
      16, 0, 0);
}

// ---------------------------------------------------------------------------
// x fp32 -> bf16 + per-(b,h) column sums (for router mean) via atomics.
__global__ void xcvt_kernel(const float* __restrict__ x, u16* __restrict__ xbf,
                            float* __restrict__ sums) {
  const int b = blockIdx.y;
  const int n0 = blockIdx.x * 16;
  const int t = threadIdx.x;
  const int h0 = t * 4;
  const size_t base = ((size_t)b * NTOK + n0) * D_MODEL + h0;
  const float* xp = x + base;
  u16* op = xbf + base;
  float a0 = 0.f, a1 = 0.f, a2 = 0.f, a3 = 0.f;
#pragma unroll
  for (int r = 0; r < 16; ++r) {
    float4 v = *(const float4*)(xp + (size_t)r * D_MODEL);
    a0 += v.x; a1 += v.y; a2 += v.z; a3 += v.w;
    u16x4 o;
    o.x = f2bf(v.x); o.y = f2bf(v.y); o.z = f2bf(v.z); o.w = f2bf(v.w);
    *(u16x4*)(op + (size_t)r * D_MODEL) = o;
  }
  float* s = sums + b * D_MODEL + h0;
  atomicAdd(s + 0, a0); atomicAdd(s + 1, a1);
  atomicAdd(s + 2, a2); atomicAdd(s + 3, a3);
}

// ---------------------------------------------------------------------------
// Router, parallel over batch: block b computes scores[b][:], argmax.
// used[] is pre-zeroed by the ws memset; plain store of 1 is race-free.
__global__ void router_kernel(const float* __restrict__ sums,
                              const float* __restrict__ Wr,
                              const float* __restrict__ br,
                              int* __restrict__ top1, int* __restrict__ used) {
  __shared__ float part[256][NEXP];
  const int b = blockIdx.x;
  const int t = threadIdx.x;
  float acc[NEXP];
#pragma unroll
  for (int e = 0; e < NEXP; ++e) acc[e] = 0.f;
  const float* s = sums + b * D_MODEL;
  for (int h = t; h < D_MODEL; h += 256) {
    const float sv = s[h];
#pragma unroll
    for (int e = 0; e < NEXP; ++e) acc[e] += sv * Wr[h * NEXP + e];
  }
#pragma unroll
  for (int e = 0; e < NEXP; ++e) part[t][e] = acc[e];
  __syncthreads();
  if (t == 0) {
    float best = -1e30f; int bi = 0;
#pragma unroll
    for (int e = 0; e < NEXP; ++e) {
      float sc = 0.f;
      for (int i = 0; i < 256; ++i) sc += part[i][e];
      sc = sc * (1.0f / (float)NTOK) + br[e];
      if (sc > best) { best = sc; bi = e; }  // first-max wins (argmax tie-break)
    }
    top1[b] = bi;
    used[bi] = 1;
  }
}

// ---------------------------------------------------------------------------
// Per-expert transpose + fp32->bf16: dst[c][r] = bf16(src[r][c]).
__global__ void wcvt_kernel(const float* __restrict__ src, u16* __restrict__ dst,
                            const int* __restrict__ used, int R, int C) {
  const int e = blockIdx.z;
  if (!used[e]) return;
  __shared__ float tile[64][65];
  const float* s = src + (size_t)e * R * C;
  u16* d = dst + (size_t)e * R * C;
  const int r0 = blockIdx.y * 64, c0 = blockIdx.x * 64;
  const int t = threadIdx.x;
#pragma unroll
  for (int i = 0; i < 16; ++i) {
    int idx = i * 256 + t;
    int r = idx >> 6, c = idx & 63;
    tile[r][c] = s[(size_t)(r0 + r) * C + (c0 + c)];
  }
  __syncthreads();
#pragma unroll
  for (int i = 0; i < 16; ++i) {
    int idx = i * 256 + t;
    int r = idx >> 6, c = idx & 63;
    d[(size_t)(c0 + r) * R + (r0 + c)] = f2bf(tile[c][r]);
  }
}

// ---------------------------------------------------------------------------
// bf16 GEMM, B^T form: C[m][n] = sum_k A[m][k]*Bt[n][k].
// Block tile 256x128, BK=64, 4 waves in 2x2; wave tile 128x64 = 8x4 of
// 16x16x32 MFMA (asymmetric tile halves LDS bytes/FLOP: 95 B/cyc/CU needed
// vs 127 for 64x64). LDS rows are 128 B (64 k-elems) stored with XOR-8
// chunk swizzle: 16B chunk c of row r lives at position c^(r&7). Staging
// applies the swizzle on the GLOBAL side of global_load_lds (per-lane
// gather; LDS side stays wave-uniform+lane*16), fragment ds_read_b128 then
// spreads 64 lanes uniformly over all 8 bank-quads -> zero bank conflicts.
template <bool RELU_BF16>
__global__ void __launch_bounds__(256, 2)
gemm_bt(const u16* __restrict__ Abase, const u16* __restrict__ Btbase,
        const float* __restrict__ biasbase, const int* __restrict__ top1,
        void* __restrict__ OutBase, int K, int Nn) {
  // A: 256 rows x 64 u16 (128 B), B: 128 rows x 64 u16 -> 48 KB
  __shared__ __align__(16) u16 smem[(256 + 128) * 64];
  u16* As = smem;
  u16* Bs = smem + 256 * 64;

  const int b = blockIdx.z;
  const int e = top1[b];
  const u16* A = Abase + (size_t)b * NTOK * K;
  const u16* Bt = Btbase + (size_t)e * Nn * K;
  const float* bias = biasbase + (size_t)e * Nn;
  const int tn = blockIdx.x, tm = blockIdx.y;
  const int tid = threadIdx.x;
  const int lane = tid & 63, wave = tid >> 6;
  const int wm = wave & 1, wn = wave >> 1;

  // staging lane map: lane l -> row l>>3 (of an 8-row group), global 16B
  // chunk (l&7)^(row&7) so that LDS position (l&7) holds swizzled data.
  const int lrow = lane >> 3;
  const int lch = (lane & 7) ^ (lrow & 7);
  const size_t laneOff = (size_t)lrow * K * 2 + (size_t)lch * 16;  // bytes
  const char* gA = (const char*)(A + (size_t)(tm * 256 + wave * 64) * K) + laneOff;
  const char* gB = (const char*)(Bt + (size_t)(tn * 128 + wave * 32) * K) + laneOff;
  u16* lA = As + wave * 64 * 64;  // wave stages A rows [w*64, w*64+64)
  u16* lB = Bs + wave * 32 * 64;  // and B rows [w*32, w*32+32)

  // fragment lane map (16x16x32): m/n = lane&15, k-chunk = lane>>4
  const int fr = lane & 15, fq = lane >> 4;
  const int s7 = fr & 7;
  // swizzled chunk offsets (u16 units) for the two k-halves of BK=64
  const int choff0 = ((0 * 4 + fq) ^ s7) * 8;
  const int choff1 = ((1 * 4 + fq) ^ s7) * 8;
  const u16* rA = As + (wm * 128 + fr) * 64;
  const u16* rB = Bs + (wn * 64 + fr) * 64;

  f32x4 acc[8][4];
#pragma unroll
  for (int i = 0; i < 8; ++i)
#pragma unroll
    for (int j = 0; j < 4; ++j) acc[i][j] = (f32x4)(0.f);

  const int KT = K >> 6;
  for (int kt = 0; kt < KT; ++kt) {
    const size_t kOff = (size_t)kt * 128;  // 64 k-elems = 128 B
#pragma unroll
    for (int i = 0; i < 8; ++i)
      gld16(gA + (size_t)i * 8 * K * 2 + kOff, lA + i * 8 * 64);
#pragma unroll
    for (int i = 0; i < 4; ++i)
      gld16(gB + (size_t)i * 8 * K * 2 + kOff, lB + i * 8 * 64);
    __syncthreads();
#pragma unroll
    for (int kh = 0; kh < 2; ++kh) {
      const int c = kh ? choff1 : choff0;
      short8 af[8], bf[4];
#pragma unroll
      for (int mt = 0; mt < 8; ++mt) af[mt] = *(const short8*)(rA + mt * 1024 + c);
#pragma unroll
      for (int nt = 0; nt < 4; ++nt) bf[nt] = *(const short8*)(rB + nt * 1024 + c);
#pragma unroll
      for (int mt = 0; mt < 8; ++mt)
#pragma unroll
        for (int nt = 0; nt < 4; ++nt)
          acc[mt][nt] = __builtin_amdgcn_mfma_f32_16x16x32_bf16(af[mt], bf[nt],
                                                                acc[mt][nt], 0, 0, 0);
    }
    __syncthreads();
  }

  // epilogue: C/D layout col=lane&15, row=4*(lane>>4)+reg
  const int row0 = tm * 256 + wm * 128 + fq * 4;
  const int col0 = tn * 128 + wn * 64 + fr;
  if constexpr (RELU_BF16) {
    u16* Out = (u16*)OutBase + (size_t)b * NTOK * Nn;
#pragma unroll
    for (int mt = 0; mt < 8; ++mt)
#pragma unroll
      for (int nt = 0; nt < 4; ++nt) {
        const int col = col0 + nt * 16;
        const float bv = bias[col];
        const int rowb = row0 + mt * 16;
#pragma unroll
        for (int r = 0; r < 4; ++r) {
          float v = acc[mt][nt][r] + bv;
          v = fmaxf(v, 0.0f);
          Out[(size_t)(rowb + r) * Nn + col] = f2bf(v);
        }
      }
  } else {
    float* Out = (float*)OutBase + (size_t)b * NTOK * Nn;
#pragma unroll
    for (int mt = 0; mt < 8; ++mt)
#pragma unroll
      for (int nt = 0; nt < 4; ++nt) {
        const int col = col0 + nt * 16;
        const float bv = bias[col];
        const int rowb = row0 + mt * 16;
#pragma unroll
        for (int r = 0; r < 4; ++r)
          Out[(size_t)(rowb + r) * Nn + col] = acc[mt][nt][r] + bv;
      }
  }
}

// ---------------------------------------------------------------------------
extern "C" void kernel_launch(void* const* d_in, const int* in_sizes, int n_in,
                              void* d_out, int out_size, void* d_ws, size_t ws_size,
                              hipStream_t stream) {
  const float* x  = (const float*)d_in[0];
  const float* Wr = (const float*)d_in[1];
  const float* br = (const float*)d_in[2];
  const float* W1 = (const float*)d_in[3];
  const float* b1 = (const float*)d_in[4];
  const float* W2 = (const float*)d_in[5];
  const float* b2 = (const float*)d_in[6];
  float* out = (float*)d_out;
  char* ws = (char*)d_ws;

  // workspace layout (~304 MB):
  int*   top1 = (int*)(ws + 0);              // 64 B
  int*   used = (int*)(ws + 64);             // 32 B   (zeroed by memset below)
  float* sums = (float*)(ws + 4096);         // 64 KB
  u16* xbf = (u16*)(ws + (1ull << 20));      // 32 MB  [B][N][H] bf16
  u16* w1t = (u16*)(ws + (48ull << 20));     // 64 MB  [E][F][H] bf16 (W1^T)
  u16* w2t = (u16*)(ws + (112ull << 20));    // 64 MB  [E][H][F] bf16 (W2^T)
  u16* hbf = (u16*)(ws + (176ull << 20));    // 128 MB [B][N][F] bf16

  hipMemsetAsync((void*)ws, 0, 4096 + D_MODEL * NB * sizeof(float), stream);

  xcvt_kernel<<<dim3(NTOK / 16, NB), 256, 0, stream>>>(x, xbf, sums);
  router_kernel<<<NB, 256, 0, stream>>>(sums, Wr, br, top1, used);
  // W1 [E][H=1024][F=4096] -> [E][F][H]
  wcvt_kernel<<<dim3(D_FF / 64, D_MODEL / 64, NEXP), 256, 0, stream>>>(
      W1, w1t, used, D_MODEL, D_FF);
  // W2 [E][F=4096][H=1024] -> [E][H][F]
  wcvt_kernel<<<dim3(D_MODEL / 64, D_FF / 64, NEXP), 256, 0, stream>>>(
      W2, w2t, used, D_FF, D_MODEL);
  // GEMM1: h = relu(x @ W1 + b1), M=1024, N=4096, K=1024, bf16 out
  gemm_bt<true><<<dim3(D_FF / 128, NTOK / 256, NB), 256, 0, stream>>>(
      xbf, w1t, b1, top1, (void*)hbf, D_MODEL, D_FF);
  // GEMM2: out = h @ W2 + b2, M=1024, N=1024, K=4096, fp32 out
  gemm_bt<false><<<dim3(D_MODEL / 128, NTOK / 256, NB), 256, 0, stream>>>(
      hbf, w2t, b2, top1, (void*)out, D_FF, D_MODEL);
}